// Round 1
// baseline (311.838 us; speedup 1.0000x reference)
//
#include <hip/hip_runtime.h>
#include <hip/hip_bf16.h>
#include <stdint.h>

// Problem constants (from reference setup_inputs)
#define NB 8
#define NA 49104
#define NC 90
#define NM 32
#define FEPS 1e-4f

// ws layout:
//   [0,64)    double reg_sum[8]
//   [64,72)   double cls_total
//   [80,112)  int npos[8]
//   [128,...) uint32 meta[NB*NA]   (bits 0..6 label, bit7 pos, bit8 baseZero)

// ---------------------------------------------------------------------------
// Kernel A: per-anchor IoU assignment + meta pack + smooth-L1 reg sum + npos
// grid = (ceil(NA/256), NB), block = 256
// ---------------------------------------------------------------------------
__global__ __launch_bounds__(256) void fl_assign(
    const float* __restrict__ anchors,      // [NA,4] (y1,x1,y2,x2)
    const float* __restrict__ regressions,  // [NB,NA,4]
    const float* __restrict__ annotations,  // [NB,NM,5] (x1,y1,x2,y2,label)
    double* __restrict__ reg_sum,           // [NB]
    int* __restrict__ npos,                 // [NB]
    uint32_t* __restrict__ meta)            // [NB*NA]
{
    const int b = blockIdx.y;
    const int a = blockIdx.x * 256 + threadIdx.x;

    __shared__ float s_ann[NM * 5];
    if (threadIdx.x < NM * 5)
        s_ann[threadIdx.x] = annotations[b * NM * 5 + threadIdx.x];
    __syncthreads();

    float rsum = 0.0f;
    int pcnt = 0;

    if (a < NA) {
        const float4 av = ((const float4*)anchors)[a];
        const float ay1 = av.x, ax1 = av.y, ay2 = av.z, ax2 = av.w;
        const float aw = ax2 - ax1, ah = ay2 - ay1;
        const float aarea = aw * ah;

        float best = -2.0f;   // iou of invalid gt is -1; strict > gives first-argmax
        int bm = 0;
        #pragma unroll 4
        for (int m = 0; m < NM; ++m) {
            const float bx1 = s_ann[m * 5 + 0];
            const float by1 = s_ann[m * 5 + 1];
            const float bx2 = s_ann[m * 5 + 2];
            const float by2 = s_ann[m * 5 + 3];
            const float lab = s_ann[m * 5 + 4];
            const float area = (bx2 - bx1) * (by2 - by1);
            float iw = fminf(ax2, bx2) - fmaxf(ax1, bx1);
            float ih = fminf(ay2, by2) - fmaxf(ay1, by1);
            iw = fmaxf(iw, 0.0f);
            ih = fmaxf(ih, 0.0f);
            const float inter = iw * ih;
            const float ua = fmaxf(aarea + area - inter, 1e-8f);
            float iou = inter / ua;
            if (lab == -1.0f) iou = -1.0f;
            if (iou > best) { best = iou; bm = m; }
        }

        const bool pos = best >= 0.5f;
        const bool bz = (best < 0.4f) || pos;          // targets base == 0.0
        const int lbl = ((int)s_ann[bm * 5 + 4]) & 0x7f;
        meta[b * NA + a] = (uint32_t)lbl | (pos ? 0x80u : 0u) | (bz ? 0x100u : 0u);

        if (pos) {
            pcnt = 1;
            const float bx1 = s_ann[bm * 5 + 0];
            const float by1 = s_ann[bm * 5 + 1];
            const float bx2 = s_ann[bm * 5 + 2];
            const float by2 = s_ann[bm * 5 + 3];
            float gw = bx2 - bx1, gh = by2 - by1;
            const float gcx = bx1 + 0.5f * gw;
            const float gcy = by1 + 0.5f * gh;   // cx/cy use unclipped w/h (ref order)
            gw = fmaxf(gw, 1.0f);
            gh = fmaxf(gh, 1.0f);
            const float acx = ax1 + 0.5f * aw;
            const float acy = ay1 + 0.5f * ah;

            const float4 rv = ((const float4*)regressions)[(size_t)b * NA + a];
            const float t0 = (gcy - acy) / ah;     // t_dy  vs reg[...,0]
            const float t1 = (gcx - acx) / aw;     // t_dx  vs reg[...,1]
            const float t2 = logf(gh / ah);        // t_dh  vs reg[...,2]
            const float t3 = logf(gw / aw);        // t_dw  vs reg[...,3]

            float d;
            d = fabsf(t0 - rv.x); rsum += (d <= 1.0f/9.0f) ? 4.5f*d*d : d - 1.0f/18.0f;
            d = fabsf(t1 - rv.y); rsum += (d <= 1.0f/9.0f) ? 4.5f*d*d : d - 1.0f/18.0f;
            d = fabsf(t2 - rv.z); rsum += (d <= 1.0f/9.0f) ? 4.5f*d*d : d - 1.0f/18.0f;
            d = fabsf(t3 - rv.w); rsum += (d <= 1.0f/9.0f) ? 4.5f*d*d : d - 1.0f/18.0f;
        }
    }

    // block reduce (4 waves of 64)
    #pragma unroll
    for (int off = 32; off > 0; off >>= 1) {
        rsum += __shfl_down(rsum, off);
        pcnt += __shfl_down(pcnt, off);
    }
    __shared__ float s_r[4];
    __shared__ int s_p[4];
    const int wave = threadIdx.x >> 6;
    if ((threadIdx.x & 63) == 0) { s_r[wave] = rsum; s_p[wave] = pcnt; }
    __syncthreads();
    if (threadIdx.x == 0) {
        const float r = s_r[0] + s_r[1] + s_r[2] + s_r[3];
        const int p = s_p[0] + s_p[1] + s_p[2] + s_p[3];
        if (p) atomicAdd(&npos[b], p);
        if (r != 0.0f) atomicAdd(&reg_sum[b], (double)r);
    }
}

// ---------------------------------------------------------------------------
// Kernel B: focal BCE over all [NB,NA,NC] elements, float4 grid-stride,
// per-chunk scale by 1/max(npos[b],1), atomic double accumulate.
// ---------------------------------------------------------------------------
__global__ __launch_bounds__(256) void fl_focal(
    const float* __restrict__ cls,
    const uint32_t* __restrict__ meta,
    const int* __restrict__ npos,
    double* __restrict__ cls_total)
{
    const int NCH = NB * NA * NC / 4;   // divisible (NA*NC % 4 == 0)
    const int stride = gridDim.x * blockDim.x;
    float acc = 0.0f;

    for (int i = blockIdx.x * blockDim.x + threadIdx.x; i < NCH; i += stride) {
        const float4 v = ((const float4*)cls)[i];
        const int e0 = i * 4;
        float s = 0.0f;
        const float pv[4] = {v.x, v.y, v.z, v.w};
        #pragma unroll
        for (int j = 0; j < 4; ++j) {
            const int e = e0 + j;
            const uint32_t aid = (uint32_t)e / (uint32_t)NC;   // magic-mul div
            const uint32_t c = (uint32_t)e - aid * (uint32_t)NC;
            const uint32_t mt = meta[aid];                      // L1-resident
            float p = fminf(fmaxf(pv[j], FEPS), 1.0f - FEPS);
            const bool pos = (mt & 0x80u) != 0u;
            const bool bz = (mt & 0x100u) != 0u;
            float loss = 0.0f;
            if (pos | bz) {
                const bool one = pos && (c == (mt & 0x7fu));
                const float pf = one ? 1.0f - p : p;
                // 0.5 * pf^2 * (-log(1-pf)) covers both t=1 and t=0 branches
                loss = 0.5f * pf * pf * (-__logf(1.0f - pf));
            }
            s += loss;
        }
        // image index; a float4 chunk never crosses an image boundary
        const uint32_t b = (uint32_t)e0 / (uint32_t)(NA * NC);
        const int np = npos[b];
        acc += s * (1.0f / (float)(np > 1 ? np : 1));
    }

    #pragma unroll
    for (int off = 32; off > 0; off >>= 1)
        acc += __shfl_down(acc, off);
    __shared__ float s_r[4];
    const int wave = threadIdx.x >> 6;
    if ((threadIdx.x & 63) == 0) s_r[wave] = acc;
    __syncthreads();
    if (threadIdx.x == 0) {
        const float r = s_r[0] + s_r[1] + s_r[2] + s_r[3];
        atomicAdd(cls_total, (double)r);
    }
}

// ---------------------------------------------------------------------------
// Kernel C: finalize both outputs
// ---------------------------------------------------------------------------
__global__ void fl_final(
    const double* __restrict__ reg_sum,
    const double* __restrict__ cls_total,
    const int* __restrict__ npos,
    float* __restrict__ out)
{
    if (threadIdx.x == 0) {
        out[0] = (float)(cls_total[0] * (1.0 / (double)NB));
        double r = 0.0;
        for (int b = 0; b < NB; ++b) {
            const int np = npos[b];
            if (np > 0) r += reg_sum[b] / (double)(4 * np);
        }
        out[1] = (float)(r * (1.0 / (double)NB));
    }
}

extern "C" void kernel_launch(void* const* d_in, const int* in_sizes, int n_in,
                              void* d_out, int out_size, void* d_ws, size_t ws_size,
                              hipStream_t stream) {
    const float* cls = (const float*)d_in[0];   // [NB,NA,NC]
    const float* reg = (const float*)d_in[1];   // [NB,NA,4]
    const float* anc = (const float*)d_in[2];   // [1,NA,4]
    const float* ann = (const float*)d_in[3];   // [NB,NM,5]
    float* out = (float*)d_out;

    char* ws = (char*)d_ws;
    double* reg_sum   = (double*)(ws + 0);      // 8 doubles
    double* cls_total = (double*)(ws + 64);     // 1 double
    int* npos         = (int*)(ws + 80);        // 8 ints
    uint32_t* meta    = (uint32_t*)(ws + 128);  // NB*NA uint32 = 1.57 MB

    // zero only the accumulator header; meta is fully overwritten each call
    hipMemsetAsync(d_ws, 0, 128, stream);

    dim3 ga((NA + 255) / 256, NB);
    fl_assign<<<ga, 256, 0, stream>>>(anc, reg, ann, reg_sum, npos, meta);
    fl_focal<<<2048, 256, 0, stream>>>(cls, meta, npos, cls_total);
    fl_final<<<1, 64, 0, stream>>>(reg_sum, cls_total, npos, out);
}